// Round 7
// baseline (226.947 us; speedup 1.0000x reference)
//
#include <hip/hip_runtime.h>
#include <hip/hip_bf16.h>

#define BB 16
#define EE 128
#define MM 64
#define DQ 768
#define DK 256
#define NT 4   // consecutive a-tiles per block (same b), phase-split staged

typedef __attribute__((ext_vector_type(8))) short short8v;   // 8 bf16 = 4 VGPR
typedef __attribute__((ext_vector_type(4))) float f32x4;

#define MFMA16(a, b, c) __builtin_amdgcn_mfma_f32_16x16x32_bf16(a, b, c, 0, 0, 0)

// raw barrier: LDS visibility only; leaves global loads/stores in flight
#define LDS_BARRIER() asm volatile("s_waitcnt lgkmcnt(0)\n\ts_barrier" ::: "memory")

__device__ __forceinline__ ushort f2bf(float f) {
  __hip_bfloat16 h = __float2bfloat16(f);
  return *reinterpret_cast<ushort*>(&h);
}
__device__ __forceinline__ uint pack2(float lo, float hi) {
  return (uint)f2bf(lo) | ((uint)f2bf(hi) << 16);
}

// ---------------------------------------------------------------------------
// K1: WfT[e][d] = sum_k Wq[d][k] * Wk[e][k]  (= (Wq @ Wk^T)^T, bf16) via MFMA.
// ---------------------------------------------------------------------------
__global__ __launch_bounds__(64) void k_wfuse(const float* __restrict__ Wq,
                                              const float* __restrict__ Wk,
                                              ushort* __restrict__ wfT) {
  const int lane = threadIdx.x & 63;
  const int lo = lane & 15, hi = lane >> 4;
  const int e0 = blockIdx.x * 16;
  const int d0 = blockIdx.y * 64;
  f32x4 acc[4] = {f32x4{0.f, 0.f, 0.f, 0.f}, f32x4{0.f, 0.f, 0.f, 0.f},
                  f32x4{0.f, 0.f, 0.f, 0.f}, f32x4{0.f, 0.f, 0.f, 0.f}};
#pragma unroll
  for (int ks = 0; ks < 8; ++ks) {
    const int k = ks * 32 + 8 * hi;
    const float4 a0 = *(const float4*)&Wk[(size_t)(e0 + lo) * DK + k];
    const float4 a1 = *(const float4*)&Wk[(size_t)(e0 + lo) * DK + k + 4];
    union { short8v v; uint u[4]; } av;
    av.u[0] = pack2(a0.x, a0.y); av.u[1] = pack2(a0.z, a0.w);
    av.u[2] = pack2(a1.x, a1.y); av.u[3] = pack2(a1.z, a1.w);
#pragma unroll
    for (int dt = 0; dt < 4; ++dt) {
      const float4 b0 = *(const float4*)&Wq[(size_t)(d0 + dt * 16 + lo) * DK + k];
      const float4 b1 = *(const float4*)&Wq[(size_t)(d0 + dt * 16 + lo) * DK + k + 4];
      union { short8v v; uint u[4]; } bv;
      bv.u[0] = pack2(b0.x, b0.y); bv.u[1] = pack2(b0.z, b0.w);
      bv.u[2] = pack2(b1.x, b1.y); bv.u[3] = pack2(b1.z, b1.w);
      acc[dt] = MFMA16(av.v, bv.v, acc[dt]);
    }
  }
#pragma unroll
  for (int dt = 0; dt < 4; ++dt)
#pragma unroll
    for (int r = 0; r < 4; ++r)
      wfT[(size_t)(e0 + 4 * hi + r) * DQ + d0 + dt * 16 + lo] = f2bf(acc[dt][r]);
}

// ---------------------------------------------------------------------------
// K2: qt[r][e] = sum_d relu(querys[r][d]) * WfT[e][d], bf16 MFMA, no LDS.
// ---------------------------------------------------------------------------
__global__ __launch_bounds__(128) void k_qt(const float* __restrict__ querys,
                                            const ushort* __restrict__ wfT,
                                            ushort* __restrict__ qt) {
  const int tid = threadIdx.x;
  const int w = tid >> 6;
  const int lane = tid & 63;
  const int lo = lane & 15, hi = lane >> 4;
  const int r0 = blockIdx.x * 32 + w * 16;
  const int e0 = blockIdx.y * 64;
  const float* qrow = querys + (size_t)(r0 + lo) * DQ;
  f32x4 acc[4] = {f32x4{0.f, 0.f, 0.f, 0.f}, f32x4{0.f, 0.f, 0.f, 0.f},
                  f32x4{0.f, 0.f, 0.f, 0.f}, f32x4{0.f, 0.f, 0.f, 0.f}};
#pragma unroll
  for (int kc = 0; kc < DQ; kc += 32) {
    const int k = kc + 8 * hi;
    const float4 a0 = *(const float4*)&qrow[k];
    const float4 a1 = *(const float4*)&qrow[k + 4];
    union { short8v v; uint u[4]; } af;
    af.u[0] = pack2(fmaxf(a0.x, 0.f), fmaxf(a0.y, 0.f));
    af.u[1] = pack2(fmaxf(a0.z, 0.f), fmaxf(a0.w, 0.f));
    af.u[2] = pack2(fmaxf(a1.x, 0.f), fmaxf(a1.y, 0.f));
    af.u[3] = pack2(fmaxf(a1.z, 0.f), fmaxf(a1.w, 0.f));
#pragma unroll
    for (int et = 0; et < 4; ++et) {
      const short8v bf = *(const short8v*)&wfT[(size_t)(e0 + et * 16 + lo) * DQ + k];
      acc[et] = MFMA16(af.v, bf, acc[et]);
    }
  }
#pragma unroll
  for (int et = 0; et < 4; ++et)
#pragma unroll
    for (int r = 0; r < 4; ++r)
      qt[(size_t)(r0 + hi * 4 + r) * DK + e0 + et * 16 + lo] = f2bf(acc[et][r]);
}

// ---------------------------------------------------------------------------
// K3: fused MFMA attention. 512 thr = 8 waves, NT=4 tiles/block, grid 512
// (2 blocks/CU = 4 waves/SIMD). SINGLE-buffered LDS with phase-split
// restaging (relu only read by QK, kT only by PV):
//   iter i: QK_i(relu) -> softmax -> P redistribute (registers)
//           BAR1 | stage_relu(i+1)  PV_i(kT) + out stores
//           BAR2 | stage_kT(i+1), kreg prefetch (i+2)
// Raw barriers (lgkmcnt only) keep global loads/stores in flight.
// LDS: relu 32K (swz (m&7)<<4), kT 32K (swz ((d&7)^((d>>3)&7))<<4),
// biasf[2][64] f32 = 64.5 KiB -> 2 blocks/CU. launch_bounds(512,4) caps
// VGPR at 128; persistent regs = kreg 32 + aq 32 -> no spill headroom kept
// by reloading wm_w from global (L1-hot) each stage.
// ---------------------------------------------------------------------------
__global__ __launch_bounds__(512, 4) void k_attn(
    const float* __restrict__ keys, const ushort* __restrict__ qt,
    const float* __restrict__ wm_w, const float* __restrict__ wm_b,
    const int* __restrict__ masks, float* __restrict__ out) {
  __shared__ ushort relu_lds[MM * DK];   // 32 KiB, single buffer
  __shared__ ushort kT_lds[DK * MM];     // 32 KiB, single buffer
  __shared__ __attribute__((aligned(16))) float biasf[2][MM];  // parity dbuf

  const int tid = threadIdx.x;
  const int w = tid >> 6;
  const int lane = tid & 63;
  const int lo = lane & 15, hi = lane >> 4;
  const int ba0 = blockIdx.x * NT;
  const int b = ba0 >> 7;                // NT | 128 -> b fixed per block

  // staging mapping: 16-lane group hi of wave w owns row pair (m0, m0+1);
  // lane lo covers float4 chunks c = lo + 16*it.
  const int m0 = w * 8 + hi * 2;
  const float4* wm4p = (const float4*)wm_w;
  const float wmb = wm_b[0];

  // qt B-fragments (cols q = w*16+lo): tile-invariant, loaded ONCE
  const ushort* qrowp = qt + ((size_t)b * EE + w * 16 + lo) * DK + 8 * hi;
  short8v aq[8];
#pragma unroll
  for (int ks = 0; ks < 8; ++ks) aq[ks] = *(const short8v*)(qrowp + 32 * ks);

  float4 kreg[8];
  int mk0, mk1;
  auto load_kreg = [&](int t) {
    const float4* p = (const float4*)(keys + (size_t)(ba0 + t) * (MM * DK));
#pragma unroll
    for (int it = 0; it < 4; ++it) {
      kreg[2 * it]     = p[(size_t)m0 * 64 + lo + 16 * it];
      kreg[2 * it + 1] = p[(size_t)(m0 + 1) * 64 + lo + 16 * it];
    }
    mk0 = masks[(size_t)(ba0 + t) * MM + m0];
    mk1 = masks[(size_t)(ba0 + t) * MM + m0 + 1];
  };

  auto stage_relu = [&](int nb) {        // relu_lds + biasf[nb] from kreg
    float bp0 = 0.f, bp1 = 0.f;
#pragma unroll
    for (int it = 0; it < 4; ++it) {
      const int c = lo + 16 * it;
      const float4 va = kreg[2 * it], vb = kreg[2 * it + 1];
      const float4 wm4 = wm4p[c];        // L1-hot after tile 0
      const float rx0 = fmaxf(va.x, 0.f), ry0 = fmaxf(va.y, 0.f);
      const float rz0 = fmaxf(va.z, 0.f), rw0 = fmaxf(va.w, 0.f);
      const float rx1 = fmaxf(vb.x, 0.f), ry1 = fmaxf(vb.y, 0.f);
      const float rz1 = fmaxf(vb.z, 0.f), rw1 = fmaxf(vb.w, 0.f);
      bp0 += rx0 * wm4.x + ry0 * wm4.y + rz0 * wm4.z + rw0 * wm4.w;
      bp1 += rx1 * wm4.x + ry1 * wm4.y + rz1 * wm4.z + rw1 * wm4.w;
      uint2 ra, rb;
      ra.x = pack2(rx0, ry0); ra.y = pack2(rz0, rw0);
      rb.x = pack2(rx1, ry1); rb.y = pack2(rz1, rw1);
      *(uint2*)((char*)relu_lds + (size_t)m0 * 512 +
                ((8 * c) ^ ((m0 & 7) << 4))) = ra;
      *(uint2*)((char*)relu_lds + (size_t)(m0 + 1) * 512 +
                ((8 * c) ^ (((m0 + 1) & 7) << 4))) = rb;
    }
    bp0 += __shfl_xor(bp0, 1); bp1 += __shfl_xor(bp1, 1);
    bp0 += __shfl_xor(bp0, 2); bp1 += __shfl_xor(bp1, 2);
    bp0 += __shfl_xor(bp0, 4); bp1 += __shfl_xor(bp1, 4);
    bp0 += __shfl_xor(bp0, 8); bp1 += __shfl_xor(bp1, 8);
    if (lo == 0) {
      biasf[nb][m0]     = mk0 ? (bp0 + wmb) : -1e12f;
      biasf[nb][m0 + 1] = mk1 ? (bp1 + wmb) : -1e12f;
    }
  };

  auto stage_kT = [&]() {                // kT_lds (raw, transposed) from kreg
#pragma unroll
    for (int it = 0; it < 4; ++it) {
      const int c = lo + 16 * it;
      const float4 va = kreg[2 * it], vb = kreg[2 * it + 1];
      const float va4[4] = {va.x, va.y, va.z, va.w};
      const float vb4[4] = {vb.x, vb.y, vb.z, vb.w};
#pragma unroll
      for (int j = 0; j < 4; ++j) {
        const int d = 4 * c + j;
        const int sw = ((d & 7) ^ ((d >> 3) & 7)) << 4;
        *(uint*)((char*)kT_lds + (size_t)d * 128 + ((2 * m0) ^ sw)) =
            pack2(va4[j], vb4[j]);
      }
    }
  };

  // ---- prologue: tile 0 fully staged; tile 1 in regs ----
  load_kreg(0);
  stage_relu(0);
  stage_kT();
  if (NT > 1) load_kreg(1);
  LDS_BARRIER();

  for (int i = 0; i < NT; ++i) {
    const int p = i & 1;

    // ================= QK^T swapped: S^T[m][q], lane owns q = w*16+lo ======
    f32x4 sacc[4] = {f32x4{0.f, 0.f, 0.f, 0.f}, f32x4{0.f, 0.f, 0.f, 0.f},
                     f32x4{0.f, 0.f, 0.f, 0.f}, f32x4{0.f, 0.f, 0.f, 0.f}};
    __builtin_amdgcn_s_setprio(1);
#pragma unroll
    for (int ks = 0; ks < 8; ++ks) {
#pragma unroll
      for (int mt = 0; mt < 4; ++mt) {
        const int m = mt * 16 + lo;
        const int k = ks * 32 + 8 * hi;
        const short8v bf = *(const short8v*)((char*)relu_lds +
                                             (size_t)m * 512 +
                                             ((2 * k) ^ ((m & 7) << 4)));
        sacc[mt] = MFMA16(bf, aq[ks], sacc[mt]);  // A = relu_k, B = qt
      }
    }
    __builtin_amdgcn_s_setprio(0);

    // ================= softmax: in-lane over 16 m + shfl_xor 16,32 =========
    const float scale = 0.036084391824351615f;  // 1/sqrt(768)
    float l[4][4];
    float mx = -3.4e38f;
#pragma unroll
    for (int mt = 0; mt < 4; ++mt) {
      const float4 bv = *(const float4*)&biasf[p][mt * 16 + hi * 4];
      const float bv4[4] = {bv.x, bv.y, bv.z, bv.w};
#pragma unroll
      for (int r = 0; r < 4; ++r) {
        l[mt][r] = fmaf(sacc[mt][r], scale, bv4[r]);
        mx = fmaxf(mx, l[mt][r]);
      }
    }
    mx = fmaxf(mx, __shfl_xor(mx, 16));
    mx = fmaxf(mx, __shfl_xor(mx, 32));
    float s = 0.f;
#pragma unroll
    for (int mt = 0; mt < 4; ++mt)
#pragma unroll
      for (int r = 0; r < 4; ++r) {
        l[mt][r] = __expf(l[mt][r] - mx);
        s += l[mt][r];
      }
    s += __shfl_xor(s, 16);
    s += __shfl_xor(s, 32);
    const float rinv = 1.f / s;

    uint pk0[4], pk1[4];
#pragma unroll
    for (int mt = 0; mt < 4; ++mt) {
      pk0[mt] = pack2(l[mt][0] * rinv, l[mt][1] * rinv);
      pk1[mt] = pack2(l[mt][2] * rinv, l[mt][3] * rinv);
    }

    // ======== redistribute P into PV B-fragment layout (16 bpermutes) ======
    const int srcA = lo + 32 * ((lane >> 4) & 1);
    const int srcB = srcA + 16;
    uint sa0[4], sa1[4], sb0[4], sb1[4];
#pragma unroll
    for (int mt = 0; mt < 4; ++mt) {
      sa0[mt] = (uint)__shfl((int)pk0[mt], srcA);
      sa1[mt] = (uint)__shfl((int)pk1[mt], srcA);
      sb0[mt] = (uint)__shfl((int)pk0[mt], srcB);
      sb1[mt] = (uint)__shfl((int)pk1[mt], srcB);
    }
    const bool ms = (hi >> 1) & 1;
    union { short8v v; uint u[4]; } pf0, pf1;
    pf0.u[0] = ms ? sa0[1] : sa0[0];
    pf0.u[1] = ms ? sa1[1] : sa1[0];
    pf0.u[2] = ms ? sb0[1] : sb0[0];
    pf0.u[3] = ms ? sb1[1] : sb1[0];
    pf1.u[0] = ms ? sa0[3] : sa0[2];
    pf1.u[1] = ms ? sa1[3] : sa1[2];
    pf1.u[2] = ms ? sb0[3] : sb0[2];
    pf1.u[3] = ms ? sb1[3] : sb1[2];

    LDS_BARRIER();   // BAR1: all QK reads of relu_lds done

    // ---- restage relu for tile i+1 (overlaps PV's kT reads below) ----
    if (i + 1 < NT) stage_relu(p ^ 1);

    // ================= PV: wave owns q = w*16..w*16+15, all 256 d ==========
    float* ob = out + ((size_t)(ba0 + i) * EE + w * 16 + lo) * DK;
    __builtin_amdgcn_s_setprio(1);
#pragma unroll
    for (int dt = 0; dt < 16; ++dt) {
      const int d = dt * 16 + lo;
      const int sw = ((d & 7) ^ ((d >> 3) & 7)) << 4;
      const short8v bk0 = *(const short8v*)((char*)kT_lds +
                                            (size_t)d * 128 + ((16 * hi) ^ sw));
      const short8v bk1 = *(const short8v*)((char*)kT_lds +
                                            (size_t)d * 128 +
                                            ((64 + 16 * hi) ^ sw));
      f32x4 o = {0.f, 0.f, 0.f, 0.f};
      o = MFMA16(bk0, pf0.v, o);   // A = kT (rows d, k=m), B = P (cols q)
      o = MFMA16(bk1, pf1.v, o);
      float4 ov;
      ov.x = o[0]; ov.y = o[1]; ov.z = o[2]; ov.w = o[3];
      *(float4*)&ob[dt * 16 + hi * 4] = ov;
    }
    __builtin_amdgcn_s_setprio(0);

    if (i + 1 < NT) {
      LDS_BARRIER();   // BAR2: all PV reads of kT_lds done
      stage_kT();                        // kT for tile i+1 (kreg still holds it)
      if (i + 2 < NT) load_kreg(i + 2);  // fire-and-forget prefetch
    }
  }
}

// ---------------------------------------------------------------------------
extern "C" void kernel_launch(void* const* d_in, const int* in_sizes, int n_in,
                              void* d_out, int out_size, void* d_ws, size_t ws_size,
                              hipStream_t stream) {
  const float* querys = (const float*)d_in[0];  // [16,128,768]
  const float* keys   = (const float*)d_in[1];  // [16,128,64,256]
  const float* Wq     = (const float*)d_in[2];  // [768,256]
  const float* Wk     = (const float*)d_in[3];  // [256,256]
  const float* Wm_w   = (const float*)d_in[4];  // [256]
  const float* Wm_b   = (const float*)d_in[5];  // [1]
  const int*   masks  = (const int*)d_in[6];    // [16,128,64]
  float* out = (float*)d_out;                   // [16,128,128,256]

  ushort* wfT   = (ushort*)d_ws;                          // 256*768 bf16
  ushort* qt_bf = (ushort*)((char*)d_ws + DK * DQ * 2);   // 2048*256 bf16

  k_wfuse<<<dim3(DK / 16, DQ / 64), 64, 0, stream>>>(Wq, Wk, wfT);
  k_qt<<<dim3((BB * EE) / 32, DK / 64), 128, 0, stream>>>(querys, wfT, qt_bf);
  k_attn<<<(BB * EE) / NT, 512, 0, stream>>>(keys, qt_bf, Wm_w, Wm_b, masks, out);
}

// Round 8
// 196.902 us; speedup vs baseline: 1.1526x; 1.1526x over previous
//
#include <hip/hip_runtime.h>
#include <hip/hip_bf16.h>

#define BB 16
#define EE 128
#define MM 64
#define DQ 768
#define DK 256
#define NT 4   // consecutive a-tiles per block (same b), phase-split staged

typedef __attribute__((ext_vector_type(8))) short short8v;   // 8 bf16 = 4 VGPR
typedef __attribute__((ext_vector_type(4))) float f32x4;

#define MFMA16(a, b, c) __builtin_amdgcn_mfma_f32_16x16x32_bf16(a, b, c, 0, 0, 0)

// raw barrier: LDS visibility only; leaves global loads/stores in flight
#define LDS_BARRIER() asm volatile("s_waitcnt lgkmcnt(0)\n\ts_barrier" ::: "memory")

__device__ __forceinline__ ushort f2bf(float f) {
  __hip_bfloat16 h = __float2bfloat16(f);
  return *reinterpret_cast<ushort*>(&h);
}
__device__ __forceinline__ uint pack2(float lo, float hi) {
  return (uint)f2bf(lo) | ((uint)f2bf(hi) << 16);
}

// ---------------------------------------------------------------------------
// K1: WfT[e][d] = sum_k Wq[d][k] * Wk[e][k]  (= (Wq @ Wk^T)^T, bf16) via MFMA.
// ---------------------------------------------------------------------------
__global__ __launch_bounds__(64) void k_wfuse(const float* __restrict__ Wq,
                                              const float* __restrict__ Wk,
                                              ushort* __restrict__ wfT) {
  const int lane = threadIdx.x & 63;
  const int lo = lane & 15, hi = lane >> 4;
  const int e0 = blockIdx.x * 16;
  const int d0 = blockIdx.y * 64;
  f32x4 acc[4] = {f32x4{0.f, 0.f, 0.f, 0.f}, f32x4{0.f, 0.f, 0.f, 0.f},
                  f32x4{0.f, 0.f, 0.f, 0.f}, f32x4{0.f, 0.f, 0.f, 0.f}};
#pragma unroll
  for (int ks = 0; ks < 8; ++ks) {
    const int k = ks * 32 + 8 * hi;
    const float4 a0 = *(const float4*)&Wk[(size_t)(e0 + lo) * DK + k];
    const float4 a1 = *(const float4*)&Wk[(size_t)(e0 + lo) * DK + k + 4];
    union { short8v v; uint u[4]; } av;
    av.u[0] = pack2(a0.x, a0.y); av.u[1] = pack2(a0.z, a0.w);
    av.u[2] = pack2(a1.x, a1.y); av.u[3] = pack2(a1.z, a1.w);
#pragma unroll
    for (int dt = 0; dt < 4; ++dt) {
      const float4 b0 = *(const float4*)&Wq[(size_t)(d0 + dt * 16 + lo) * DK + k];
      const float4 b1 = *(const float4*)&Wq[(size_t)(d0 + dt * 16 + lo) * DK + k + 4];
      union { short8v v; uint u[4]; } bv;
      bv.u[0] = pack2(b0.x, b0.y); bv.u[1] = pack2(b0.z, b0.w);
      bv.u[2] = pack2(b1.x, b1.y); bv.u[3] = pack2(b1.z, b1.w);
      acc[dt] = MFMA16(av.v, bv.v, acc[dt]);
    }
  }
#pragma unroll
  for (int dt = 0; dt < 4; ++dt)
#pragma unroll
    for (int r = 0; r < 4; ++r)
      wfT[(size_t)(e0 + 4 * hi + r) * DQ + d0 + dt * 16 + lo] = f2bf(acc[dt][r]);
}

// ---------------------------------------------------------------------------
// K2: qt[r][e] = sum_d relu(querys[r][d]) * WfT[e][d], bf16 MFMA, no LDS.
// ---------------------------------------------------------------------------
__global__ __launch_bounds__(128) void k_qt(const float* __restrict__ querys,
                                            const ushort* __restrict__ wfT,
                                            ushort* __restrict__ qt) {
  const int tid = threadIdx.x;
  const int w = tid >> 6;
  const int lane = tid & 63;
  const int lo = lane & 15, hi = lane >> 4;
  const int r0 = blockIdx.x * 32 + w * 16;
  const int e0 = blockIdx.y * 64;
  const float* qrow = querys + (size_t)(r0 + lo) * DQ;
  f32x4 acc[4] = {f32x4{0.f, 0.f, 0.f, 0.f}, f32x4{0.f, 0.f, 0.f, 0.f},
                  f32x4{0.f, 0.f, 0.f, 0.f}, f32x4{0.f, 0.f, 0.f, 0.f}};
#pragma unroll
  for (int kc = 0; kc < DQ; kc += 32) {
    const int k = kc + 8 * hi;
    const float4 a0 = *(const float4*)&qrow[k];
    const float4 a1 = *(const float4*)&qrow[k + 4];
    union { short8v v; uint u[4]; } af;
    af.u[0] = pack2(fmaxf(a0.x, 0.f), fmaxf(a0.y, 0.f));
    af.u[1] = pack2(fmaxf(a0.z, 0.f), fmaxf(a0.w, 0.f));
    af.u[2] = pack2(fmaxf(a1.x, 0.f), fmaxf(a1.y, 0.f));
    af.u[3] = pack2(fmaxf(a1.z, 0.f), fmaxf(a1.w, 0.f));
#pragma unroll
    for (int et = 0; et < 4; ++et) {
      const short8v bf = *(const short8v*)&wfT[(size_t)(e0 + et * 16 + lo) * DQ + k];
      acc[et] = MFMA16(af.v, bf, acc[et]);
    }
  }
#pragma unroll
  for (int et = 0; et < 4; ++et)
#pragma unroll
    for (int r = 0; r < 4; ++r)
      qt[(size_t)(r0 + hi * 4 + r) * DK + e0 + et * 16 + lo] = f2bf(acc[et][r]);
}

// ---------------------------------------------------------------------------
// K3: fused MFMA attention. 512 thr = 8 waves, NT=4 tiles/block, grid 512
// (2 blocks/CU = 4 waves/SIMD). SINGLE-buffered LDS, phase-split restaging:
//   iter i: [reload aq from L2] QK_i(relu) -> softmax -> P redistribute
//           BAR1 | stage_relu(i+1)  PV_i(kT) + out stores
//           BAR2 | stage_kT(i+1), kreg prefetch (i+2)
// Register discipline (round-7 spill post-mortem): qt fragments are NOT
// persistent — reloaded per tile from L2 behind an asm opacity barrier so
// LICM can't hoist them. Persistent state = kreg(32) + addresses only.
// LDS: relu 32K (swz (m&7)<<4), kT 32K (swz ((d&7)^((d>>3)&7))<<4),
// biasf[2][64] f32 = 64.5 KiB.
// ---------------------------------------------------------------------------
__global__ __launch_bounds__(512, 4) void k_attn(
    const float* __restrict__ keys, const ushort* __restrict__ qt,
    const float* __restrict__ wm_w, const float* __restrict__ wm_b,
    const int* __restrict__ masks, float* __restrict__ out) {
  __shared__ ushort relu_lds[MM * DK];   // 32 KiB, single buffer
  __shared__ ushort kT_lds[DK * MM];     // 32 KiB, single buffer
  __shared__ __attribute__((aligned(16))) float biasf[2][MM];  // parity dbuf

  const int tid = threadIdx.x;
  const int w = tid >> 6;
  const int lane = tid & 63;
  const int lo = lane & 15, hi = lane >> 4;
  const int ba0 = blockIdx.x * NT;
  const int b = ba0 >> 7;                // NT | 128 -> b fixed per block

  // staging mapping: 16-lane group hi of wave w owns row pair (m0, m0+1);
  // lane lo covers float4 chunks c = lo + 16*it.
  const int m0 = w * 8 + hi * 2;
  const float4* wm4p = (const float4*)wm_w;
  const float wmb = wm_b[0];

  // qt row base for this lane (fragments reloaded per tile, see loop)
  const ushort* qrowp = qt + ((size_t)b * EE + w * 16 + lo) * DK + 8 * hi;

  float4 kreg[8];
  int mk0, mk1;
  auto load_kreg = [&](int t) {
    const float4* p = (const float4*)(keys + (size_t)(ba0 + t) * (MM * DK));
#pragma unroll
    for (int it = 0; it < 4; ++it) {
      kreg[2 * it]     = p[(size_t)m0 * 64 + lo + 16 * it];
      kreg[2 * it + 1] = p[(size_t)(m0 + 1) * 64 + lo + 16 * it];
    }
    mk0 = masks[(size_t)(ba0 + t) * MM + m0];
    mk1 = masks[(size_t)(ba0 + t) * MM + m0 + 1];
  };

  auto stage_relu = [&](int nb) {        // relu_lds + biasf[nb] from kreg
    float bp0 = 0.f, bp1 = 0.f;
#pragma unroll
    for (int it = 0; it < 4; ++it) {
      const int c = lo + 16 * it;
      const float4 va = kreg[2 * it], vb = kreg[2 * it + 1];
      const float4 wm4 = wm4p[c];        // L1-hot after tile 0
      const float rx0 = fmaxf(va.x, 0.f), ry0 = fmaxf(va.y, 0.f);
      const float rz0 = fmaxf(va.z, 0.f), rw0 = fmaxf(va.w, 0.f);
      const float rx1 = fmaxf(vb.x, 0.f), ry1 = fmaxf(vb.y, 0.f);
      const float rz1 = fmaxf(vb.z, 0.f), rw1 = fmaxf(vb.w, 0.f);
      bp0 += rx0 * wm4.x + ry0 * wm4.y + rz0 * wm4.z + rw0 * wm4.w;
      bp1 += rx1 * wm4.x + ry1 * wm4.y + rz1 * wm4.z + rw1 * wm4.w;
      uint2 ra, rb;
      ra.x = pack2(rx0, ry0); ra.y = pack2(rz0, rw0);
      rb.x = pack2(rx1, ry1); rb.y = pack2(rz1, rw1);
      *(uint2*)((char*)relu_lds + (size_t)m0 * 512 +
                ((8 * c) ^ ((m0 & 7) << 4))) = ra;
      *(uint2*)((char*)relu_lds + (size_t)(m0 + 1) * 512 +
                ((8 * c) ^ (((m0 + 1) & 7) << 4))) = rb;
    }
    bp0 += __shfl_xor(bp0, 1); bp1 += __shfl_xor(bp1, 1);
    bp0 += __shfl_xor(bp0, 2); bp1 += __shfl_xor(bp1, 2);
    bp0 += __shfl_xor(bp0, 4); bp1 += __shfl_xor(bp1, 4);
    bp0 += __shfl_xor(bp0, 8); bp1 += __shfl_xor(bp1, 8);
    if (lo == 0) {
      biasf[nb][m0]     = mk0 ? (bp0 + wmb) : -1e12f;
      biasf[nb][m0 + 1] = mk1 ? (bp1 + wmb) : -1e12f;
    }
  };

  auto stage_kT = [&]() {                // kT_lds (raw, transposed) from kreg
#pragma unroll
    for (int it = 0; it < 4; ++it) {
      const int c = lo + 16 * it;
      const float4 va = kreg[2 * it], vb = kreg[2 * it + 1];
      const float va4[4] = {va.x, va.y, va.z, va.w};
      const float vb4[4] = {vb.x, vb.y, vb.z, vb.w};
#pragma unroll
      for (int j = 0; j < 4; ++j) {
        const int d = 4 * c + j;
        const int sw = ((d & 7) ^ ((d >> 3) & 7)) << 4;
        *(uint*)((char*)kT_lds + (size_t)d * 128 + ((2 * m0) ^ sw)) =
            pack2(va4[j], vb4[j]);
      }
    }
  };

  // ---- prologue: tile 0 fully staged; tile 1 in regs ----
  load_kreg(0);
  stage_relu(0);
  stage_kT();
  if (NT > 1) load_kreg(1);
  LDS_BARRIER();

  for (int i = 0; i < NT; ++i) {
    const int p = i & 1;

    // ---- reload qt B-fragments from L2 (transient; opacity barrier
    //      prevents LICM from making these 32 persistent VGPRs) ----
    const ushort* qp = qrowp;
    asm volatile("" : "+v"(qp));
    short8v aq[8];
#pragma unroll
    for (int ks = 0; ks < 8; ++ks) aq[ks] = *(const short8v*)(qp + 32 * ks);

    // ================= QK^T swapped: S^T[m][q], lane owns q = w*16+lo ======
    f32x4 sacc[4] = {f32x4{0.f, 0.f, 0.f, 0.f}, f32x4{0.f, 0.f, 0.f, 0.f},
                     f32x4{0.f, 0.f, 0.f, 0.f}, f32x4{0.f, 0.f, 0.f, 0.f}};
    __builtin_amdgcn_s_setprio(1);
#pragma unroll
    for (int ks = 0; ks < 8; ++ks) {
#pragma unroll
      for (int mt = 0; mt < 4; ++mt) {
        const int m = mt * 16 + lo;
        const int k = ks * 32 + 8 * hi;
        const short8v bf = *(const short8v*)((char*)relu_lds +
                                             (size_t)m * 512 +
                                             ((2 * k) ^ ((m & 7) << 4)));
        sacc[mt] = MFMA16(bf, aq[ks], sacc[mt]);  // A = relu_k, B = qt
      }
    }
    __builtin_amdgcn_s_setprio(0);

    // ================= softmax: in-lane over 16 m + shfl_xor 16,32 =========
    const float scale = 0.036084391824351615f;  // 1/sqrt(768)
    float l[4][4];
    float mx = -3.4e38f;
#pragma unroll
    for (int mt = 0; mt < 4; ++mt) {
      const float4 bv = *(const float4*)&biasf[p][mt * 16 + hi * 4];
      const float bv4[4] = {bv.x, bv.y, bv.z, bv.w};
#pragma unroll
      for (int r = 0; r < 4; ++r) {
        l[mt][r] = fmaf(sacc[mt][r], scale, bv4[r]);
        mx = fmaxf(mx, l[mt][r]);
      }
    }
    mx = fmaxf(mx, __shfl_xor(mx, 16));
    mx = fmaxf(mx, __shfl_xor(mx, 32));
    float s = 0.f;
#pragma unroll
    for (int mt = 0; mt < 4; ++mt)
#pragma unroll
      for (int r = 0; r < 4; ++r) {
        l[mt][r] = __expf(l[mt][r] - mx);
        s += l[mt][r];
      }
    s += __shfl_xor(s, 16);
    s += __shfl_xor(s, 32);
    const float rinv = 1.f / s;

    uint pk0[4], pk1[4];
#pragma unroll
    for (int mt = 0; mt < 4; ++mt) {
      pk0[mt] = pack2(l[mt][0] * rinv, l[mt][1] * rinv);
      pk1[mt] = pack2(l[mt][2] * rinv, l[mt][3] * rinv);
    }

    // ======== redistribute P into PV B-fragment layout (16 bpermutes) ======
    const int srcA = lo + 32 * ((lane >> 4) & 1);
    const int srcB = srcA + 16;
    uint sa0[4], sa1[4], sb0[4], sb1[4];
#pragma unroll
    for (int mt = 0; mt < 4; ++mt) {
      sa0[mt] = (uint)__shfl((int)pk0[mt], srcA);
      sa1[mt] = (uint)__shfl((int)pk1[mt], srcA);
      sb0[mt] = (uint)__shfl((int)pk0[mt], srcB);
      sb1[mt] = (uint)__shfl((int)pk1[mt], srcB);
    }
    const bool ms = (hi >> 1) & 1;
    union { short8v v; uint u[4]; } pf0, pf1;
    pf0.u[0] = ms ? sa0[1] : sa0[0];
    pf0.u[1] = ms ? sa1[1] : sa1[0];
    pf0.u[2] = ms ? sb0[1] : sb0[0];
    pf0.u[3] = ms ? sb1[1] : sb1[0];
    pf1.u[0] = ms ? sa0[3] : sa0[2];
    pf1.u[1] = ms ? sa1[3] : sa1[2];
    pf1.u[2] = ms ? sb0[3] : sb0[2];
    pf1.u[3] = ms ? sb1[3] : sb1[2];

    LDS_BARRIER();   // BAR1: all QK reads of relu_lds done

    // ---- restage relu for tile i+1 (overlaps PV's kT reads below) ----
    if (i + 1 < NT) stage_relu(p ^ 1);

    // ================= PV: wave owns q = w*16..w*16+15, all 256 d ==========
    float* ob = out + ((size_t)(ba0 + i) * EE + w * 16 + lo) * DK;
    __builtin_amdgcn_s_setprio(1);
#pragma unroll
    for (int dt = 0; dt < 16; ++dt) {
      const int d = dt * 16 + lo;
      const int sw = ((d & 7) ^ ((d >> 3) & 7)) << 4;
      const short8v bk0 = *(const short8v*)((char*)kT_lds +
                                            (size_t)d * 128 + ((16 * hi) ^ sw));
      const short8v bk1 = *(const short8v*)((char*)kT_lds +
                                            (size_t)d * 128 +
                                            ((64 + 16 * hi) ^ sw));
      f32x4 o = {0.f, 0.f, 0.f, 0.f};
      o = MFMA16(bk0, pf0.v, o);   // A = kT (rows d, k=m), B = P (cols q)
      o = MFMA16(bk1, pf1.v, o);
      float4 ov;
      ov.x = o[0]; ov.y = o[1]; ov.z = o[2]; ov.w = o[3];
      *(float4*)&ob[dt * 16 + hi * 4] = ov;
    }
    __builtin_amdgcn_s_setprio(0);

    if (i + 1 < NT) {
      LDS_BARRIER();   // BAR2: all PV reads of kT_lds done
      stage_kT();                        // kT for tile i+1 (kreg still holds it)
      if (i + 2 < NT) load_kreg(i + 2);  // fire-and-forget prefetch
    }
  }
}

// ---------------------------------------------------------------------------
extern "C" void kernel_launch(void* const* d_in, const int* in_sizes, int n_in,
                              void* d_out, int out_size, void* d_ws, size_t ws_size,
                              hipStream_t stream) {
  const float* querys = (const float*)d_in[0];  // [16,128,768]
  const float* keys   = (const float*)d_in[1];  // [16,128,64,256]
  const float* Wq     = (const float*)d_in[2];  // [768,256]
  const float* Wk     = (const float*)d_in[3];  // [256,256]
  const float* Wm_w   = (const float*)d_in[4];  // [256]
  const float* Wm_b   = (const float*)d_in[5];  // [1]
  const int*   masks  = (const int*)d_in[6];    // [16,128,64]
  float* out = (float*)d_out;                   // [16,128,128,256]

  ushort* wfT   = (ushort*)d_ws;                          // 256*768 bf16
  ushort* qt_bf = (ushort*)((char*)d_ws + DK * DQ * 2);   // 2048*256 bf16

  k_wfuse<<<dim3(DK / 16, DQ / 64), 64, 0, stream>>>(Wq, Wk, wfT);
  k_qt<<<dim3((BB * EE) / 32, DK / 64), 128, 0, stream>>>(querys, wfT, qt_bf);
  k_attn<<<(BB * EE) / NT, 512, 0, stream>>>(keys, qt_bf, Wm_w, Wm_b, masks, out);
}

// Round 9
// 187.532 us; speedup vs baseline: 1.2102x; 1.0500x over previous
//
#include <hip/hip_runtime.h>
#include <hip/hip_bf16.h>

#define BB 16
#define EE 128
#define MM 64
#define DQ 768
#define DK 256
#define NT 4   // consecutive a-tiles per block (same b), phase-split staged

typedef __attribute__((ext_vector_type(8))) short short8v;   // 8 bf16 = 4 VGPR
typedef __attribute__((ext_vector_type(4))) float f32x4;

#define MFMA16(a, b, c) __builtin_amdgcn_mfma_f32_16x16x32_bf16(a, b, c, 0, 0, 0)

// raw barrier: LDS visibility only; leaves global loads/stores in flight
#define LDS_BARRIER() asm volatile("s_waitcnt lgkmcnt(0)\n\ts_barrier" ::: "memory")

__device__ __forceinline__ ushort f2bf(float f) {
  __hip_bfloat16 h = __float2bfloat16(f);
  return *reinterpret_cast<ushort*>(&h);
}
__device__ __forceinline__ uint pack2(float lo, float hi) {
  return (uint)f2bf(lo) | ((uint)f2bf(hi) << 16);
}

// ---------------------------------------------------------------------------
// K1: WfT[e][d] = sum_k Wq[d][k] * Wk[e][k]  (= (Wq @ Wk^T)^T, bf16) via MFMA.
// ---------------------------------------------------------------------------
__global__ __launch_bounds__(64) void k_wfuse(const float* __restrict__ Wq,
                                              const float* __restrict__ Wk,
                                              ushort* __restrict__ wfT) {
  const int lane = threadIdx.x & 63;
  const int lo = lane & 15, hi = lane >> 4;
  const int e0 = blockIdx.x * 16;
  const int d0 = blockIdx.y * 64;
  f32x4 acc[4] = {f32x4{0.f, 0.f, 0.f, 0.f}, f32x4{0.f, 0.f, 0.f, 0.f},
                  f32x4{0.f, 0.f, 0.f, 0.f}, f32x4{0.f, 0.f, 0.f, 0.f}};
#pragma unroll
  for (int ks = 0; ks < 8; ++ks) {
    const int k = ks * 32 + 8 * hi;
    const float4 a0 = *(const float4*)&Wk[(size_t)(e0 + lo) * DK + k];
    const float4 a1 = *(const float4*)&Wk[(size_t)(e0 + lo) * DK + k + 4];
    union { short8v v; uint u[4]; } av;
    av.u[0] = pack2(a0.x, a0.y); av.u[1] = pack2(a0.z, a0.w);
    av.u[2] = pack2(a1.x, a1.y); av.u[3] = pack2(a1.z, a1.w);
#pragma unroll
    for (int dt = 0; dt < 4; ++dt) {
      const float4 b0 = *(const float4*)&Wq[(size_t)(d0 + dt * 16 + lo) * DK + k];
      const float4 b1 = *(const float4*)&Wq[(size_t)(d0 + dt * 16 + lo) * DK + k + 4];
      union { short8v v; uint u[4]; } bv;
      bv.u[0] = pack2(b0.x, b0.y); bv.u[1] = pack2(b0.z, b0.w);
      bv.u[2] = pack2(b1.x, b1.y); bv.u[3] = pack2(b1.z, b1.w);
      acc[dt] = MFMA16(av.v, bv.v, acc[dt]);
    }
  }
#pragma unroll
  for (int dt = 0; dt < 4; ++dt)
#pragma unroll
    for (int r = 0; r < 4; ++r)
      wfT[(size_t)(e0 + 4 * hi + r) * DQ + d0 + dt * 16 + lo] = f2bf(acc[dt][r]);
}

// ---------------------------------------------------------------------------
// K2: qt[r][e] = sum_d relu(querys[r][d]) * WfT[e][d], bf16 MFMA, no LDS.
// ---------------------------------------------------------------------------
__global__ __launch_bounds__(128) void k_qt(const float* __restrict__ querys,
                                            const ushort* __restrict__ wfT,
                                            ushort* __restrict__ qt) {
  const int tid = threadIdx.x;
  const int w = tid >> 6;
  const int lane = tid & 63;
  const int lo = lane & 15, hi = lane >> 4;
  const int r0 = blockIdx.x * 32 + w * 16;
  const int e0 = blockIdx.y * 64;
  const float* qrow = querys + (size_t)(r0 + lo) * DQ;
  f32x4 acc[4] = {f32x4{0.f, 0.f, 0.f, 0.f}, f32x4{0.f, 0.f, 0.f, 0.f},
                  f32x4{0.f, 0.f, 0.f, 0.f}, f32x4{0.f, 0.f, 0.f, 0.f}};
#pragma unroll
  for (int kc = 0; kc < DQ; kc += 32) {
    const int k = kc + 8 * hi;
    const float4 a0 = *(const float4*)&qrow[k];
    const float4 a1 = *(const float4*)&qrow[k + 4];
    union { short8v v; uint u[4]; } af;
    af.u[0] = pack2(fmaxf(a0.x, 0.f), fmaxf(a0.y, 0.f));
    af.u[1] = pack2(fmaxf(a0.z, 0.f), fmaxf(a0.w, 0.f));
    af.u[2] = pack2(fmaxf(a1.x, 0.f), fmaxf(a1.y, 0.f));
    af.u[3] = pack2(fmaxf(a1.z, 0.f), fmaxf(a1.w, 0.f));
#pragma unroll
    for (int et = 0; et < 4; ++et) {
      const short8v bf = *(const short8v*)&wfT[(size_t)(e0 + et * 16 + lo) * DQ + k];
      acc[et] = MFMA16(af.v, bf, acc[et]);
    }
  }
#pragma unroll
  for (int et = 0; et < 4; ++et)
#pragma unroll
    for (int r = 0; r < 4; ++r)
      qt[(size_t)(r0 + hi * 4 + r) * DK + e0 + et * 16 + lo] = f2bf(acc[et][r]);
}

// ---------------------------------------------------------------------------
// K3: fused MFMA attention. 512 thr = 8 waves, NT=4 tiles/block, grid 512
// (2 blocks/CU = 4 waves/SIMD). SINGLE-buffered LDS, phase-split restaging,
// ZERO persistent staging registers (round-8 post-mortem: reg-prefetch is
// what spilled; schedule kept, registers shed):
//   iter i: [reload aq from L2] QK_i(relu) -> softmax -> P redistribute
//           BAR1 | stage_relu(i+1): GLOBAL->relu_lds (overlaps PV's kT phase)
//                  PV_i(kT) + out stores
//           BAR2 | stage_kT(i+1): re-read same lines (L1/L2-hot) -> kT_lds
// Raw barriers (lgkmcnt only) keep global loads/stores in flight.
// LDS: relu 32K (swz (m&7)<<4), kT 32K (swz ((d&7)^((d>>3)&7))<<4),
// biasf[2][64] f32 = 64.5 KiB. Persistent VGPRs ~= addresses only.
// ---------------------------------------------------------------------------
__global__ __launch_bounds__(512, 4) void k_attn(
    const float* __restrict__ keys, const ushort* __restrict__ qt,
    const float* __restrict__ wm_w, const float* __restrict__ wm_b,
    const int* __restrict__ masks, float* __restrict__ out) {
  __shared__ ushort relu_lds[MM * DK];   // 32 KiB, single buffer
  __shared__ ushort kT_lds[DK * MM];     // 32 KiB, single buffer
  __shared__ __attribute__((aligned(16))) float biasf[2][MM];  // parity dbuf

  const int tid = threadIdx.x;
  const int w = tid >> 6;
  const int lane = tid & 63;
  const int lo = lane & 15, hi = lane >> 4;
  const int ba0 = blockIdx.x * NT;
  const int b = ba0 >> 7;                // NT | 128 -> b fixed per block

  // staging mapping: 16-lane group hi of wave w owns row pair (m0, m0+1);
  // lane lo covers float4 chunks c = lo + 16*it.
  const int m0 = w * 8 + hi * 2;
  const float4* wm4p = (const float4*)wm_w;
  const float wmb = wm_b[0];

  // qt row base for this lane (fragments reloaded per tile, see loop)
  const ushort* qrowp = qt + ((size_t)b * EE + w * 16 + lo) * DK + 8 * hi;

  // stage_relu: keys[t] GLOBAL -> relu_lds (bf16, swizzled) + biasf[nb].
  // Loads are transient (consumed within the function) — no persistent regs.
  auto stage_relu = [&](int t, int nb) {
    const float4* p = (const float4*)(keys + (size_t)(ba0 + t) * (MM * DK));
    float4 va[4], vb[4];
#pragma unroll
    for (int it = 0; it < 4; ++it) {
      va[it] = p[(size_t)m0 * 64 + lo + 16 * it];
      vb[it] = p[(size_t)(m0 + 1) * 64 + lo + 16 * it];
    }
    const int mk0 = masks[(size_t)(ba0 + t) * MM + m0];
    const int mk1 = masks[(size_t)(ba0 + t) * MM + m0 + 1];
    float bp0 = 0.f, bp1 = 0.f;
#pragma unroll
    for (int it = 0; it < 4; ++it) {
      const int c = lo + 16 * it;
      const float4 wm4 = wm4p[c];        // L1-hot after tile 0
      const float rx0 = fmaxf(va[it].x, 0.f), ry0 = fmaxf(va[it].y, 0.f);
      const float rz0 = fmaxf(va[it].z, 0.f), rw0 = fmaxf(va[it].w, 0.f);
      const float rx1 = fmaxf(vb[it].x, 0.f), ry1 = fmaxf(vb[it].y, 0.f);
      const float rz1 = fmaxf(vb[it].z, 0.f), rw1 = fmaxf(vb[it].w, 0.f);
      bp0 += rx0 * wm4.x + ry0 * wm4.y + rz0 * wm4.z + rw0 * wm4.w;
      bp1 += rx1 * wm4.x + ry1 * wm4.y + rz1 * wm4.z + rw1 * wm4.w;
      uint2 ra, rb;
      ra.x = pack2(rx0, ry0); ra.y = pack2(rz0, rw0);
      rb.x = pack2(rx1, ry1); rb.y = pack2(rz1, rw1);
      *(uint2*)((char*)relu_lds + (size_t)m0 * 512 +
                ((8 * c) ^ ((m0 & 7) << 4))) = ra;
      *(uint2*)((char*)relu_lds + (size_t)(m0 + 1) * 512 +
                ((8 * c) ^ (((m0 + 1) & 7) << 4))) = rb;
    }
    bp0 += __shfl_xor(bp0, 1); bp1 += __shfl_xor(bp1, 1);
    bp0 += __shfl_xor(bp0, 2); bp1 += __shfl_xor(bp1, 2);
    bp0 += __shfl_xor(bp0, 4); bp1 += __shfl_xor(bp1, 4);
    bp0 += __shfl_xor(bp0, 8); bp1 += __shfl_xor(bp1, 8);
    if (lo == 0) {
      biasf[nb][m0]     = mk0 ? (bp0 + wmb) : -1e12f;
      biasf[nb][m0 + 1] = mk1 ? (bp1 + wmb) : -1e12f;
    }
  };

  // stage_kT: keys[t] (L1/L2-hot — same lines stage_relu just fetched)
  // -> kT_lds (raw bf16, transposed, swizzled).
  auto stage_kT = [&](int t) {
    const float4* p = (const float4*)(keys + (size_t)(ba0 + t) * (MM * DK));
    float4 va[4], vb[4];
#pragma unroll
    for (int it = 0; it < 4; ++it) {
      va[it] = p[(size_t)m0 * 64 + lo + 16 * it];
      vb[it] = p[(size_t)(m0 + 1) * 64 + lo + 16 * it];
    }
#pragma unroll
    for (int it = 0; it < 4; ++it) {
      const int c = lo + 16 * it;
      const float va4[4] = {va[it].x, va[it].y, va[it].z, va[it].w};
      const float vb4[4] = {vb[it].x, vb[it].y, vb[it].z, vb[it].w};
#pragma unroll
      for (int j = 0; j < 4; ++j) {
        const int d = 4 * c + j;
        const int sw = ((d & 7) ^ ((d >> 3) & 7)) << 4;
        *(uint*)((char*)kT_lds + (size_t)d * 128 + ((2 * m0) ^ sw)) =
            pack2(va4[j], vb4[j]);
      }
    }
  };

  // ---- prologue: tile 0 fully staged ----
  stage_relu(0, 0);
  stage_kT(0);
  LDS_BARRIER();

  for (int i = 0; i < NT; ++i) {
    const int p = i & 1;

    // ---- reload qt B-fragments from L2 (transient; opacity barrier
    //      prevents LICM from making these 32 persistent VGPRs) ----
    const ushort* qp = qrowp;
    asm volatile("" : "+v"(qp));
    short8v aq[8];
#pragma unroll
    for (int ks = 0; ks < 8; ++ks) aq[ks] = *(const short8v*)(qp + 32 * ks);

    // ================= QK^T swapped: S^T[m][q], lane owns q = w*16+lo ======
    f32x4 sacc[4] = {f32x4{0.f, 0.f, 0.f, 0.f}, f32x4{0.f, 0.f, 0.f, 0.f},
                     f32x4{0.f, 0.f, 0.f, 0.f}, f32x4{0.f, 0.f, 0.f, 0.f}};
    __builtin_amdgcn_s_setprio(1);
#pragma unroll
    for (int ks = 0; ks < 8; ++ks) {
#pragma unroll
      for (int mt = 0; mt < 4; ++mt) {
        const int m = mt * 16 + lo;
        const int k = ks * 32 + 8 * hi;
        const short8v bf = *(const short8v*)((char*)relu_lds +
                                             (size_t)m * 512 +
                                             ((2 * k) ^ ((m & 7) << 4)));
        sacc[mt] = MFMA16(bf, aq[ks], sacc[mt]);  // A = relu_k, B = qt
      }
    }
    __builtin_amdgcn_s_setprio(0);

    // ================= softmax: in-lane over 16 m + shfl_xor 16,32 =========
    const float scale = 0.036084391824351615f;  // 1/sqrt(768)
    float l[4][4];
    float mx = -3.4e38f;
#pragma unroll
    for (int mt = 0; mt < 4; ++mt) {
      const float4 bv = *(const float4*)&biasf[p][mt * 16 + hi * 4];
      const float bv4[4] = {bv.x, bv.y, bv.z, bv.w};
#pragma unroll
      for (int r = 0; r < 4; ++r) {
        l[mt][r] = fmaf(sacc[mt][r], scale, bv4[r]);
        mx = fmaxf(mx, l[mt][r]);
      }
    }
    mx = fmaxf(mx, __shfl_xor(mx, 16));
    mx = fmaxf(mx, __shfl_xor(mx, 32));
    float s = 0.f;
#pragma unroll
    for (int mt = 0; mt < 4; ++mt)
#pragma unroll
      for (int r = 0; r < 4; ++r) {
        l[mt][r] = __expf(l[mt][r] - mx);
        s += l[mt][r];
      }
    s += __shfl_xor(s, 16);
    s += __shfl_xor(s, 32);
    const float rinv = 1.f / s;

    uint pk0[4], pk1[4];
#pragma unroll
    for (int mt = 0; mt < 4; ++mt) {
      pk0[mt] = pack2(l[mt][0] * rinv, l[mt][1] * rinv);
      pk1[mt] = pack2(l[mt][2] * rinv, l[mt][3] * rinv);
    }

    // ======== redistribute P into PV B-fragment layout (16 bpermutes) ======
    const int srcA = lo + 32 * ((lane >> 4) & 1);
    const int srcB = srcA + 16;
    uint sa0[4], sa1[4], sb0[4], sb1[4];
#pragma unroll
    for (int mt = 0; mt < 4; ++mt) {
      sa0[mt] = (uint)__shfl((int)pk0[mt], srcA);
      sa1[mt] = (uint)__shfl((int)pk1[mt], srcA);
      sb0[mt] = (uint)__shfl((int)pk0[mt], srcB);
      sb1[mt] = (uint)__shfl((int)pk1[mt], srcB);
    }
    const bool ms = (hi >> 1) & 1;
    union { short8v v; uint u[4]; } pf0, pf1;
    pf0.u[0] = ms ? sa0[1] : sa0[0];
    pf0.u[1] = ms ? sa1[1] : sa1[0];
    pf0.u[2] = ms ? sb0[1] : sb0[0];
    pf0.u[3] = ms ? sb1[1] : sb1[0];
    pf1.u[0] = ms ? sa0[3] : sa0[2];
    pf1.u[1] = ms ? sa1[3] : sa1[2];
    pf1.u[2] = ms ? sb0[3] : sb0[2];
    pf1.u[3] = ms ? sb1[3] : sb1[2];

    LDS_BARRIER();   // BAR1: all QK reads of relu_lds done

    // ---- restage relu for tile i+1 from GLOBAL (overlaps PV below) ----
    if (i + 1 < NT) stage_relu(i + 1, p ^ 1);

    // ================= PV: wave owns q = w*16..w*16+15, all 256 d ==========
    float* ob = out + ((size_t)(ba0 + i) * EE + w * 16 + lo) * DK;
    __builtin_amdgcn_s_setprio(1);
#pragma unroll
    for (int dt = 0; dt < 16; ++dt) {
      const int d = dt * 16 + lo;
      const int sw = ((d & 7) ^ ((d >> 3) & 7)) << 4;
      const short8v bk0 = *(const short8v*)((char*)kT_lds +
                                            (size_t)d * 128 + ((16 * hi) ^ sw));
      const short8v bk1 = *(const short8v*)((char*)kT_lds +
                                            (size_t)d * 128 +
                                            ((64 + 16 * hi) ^ sw));
      f32x4 o = {0.f, 0.f, 0.f, 0.f};
      o = MFMA16(bk0, pf0.v, o);   // A = kT (rows d, k=m), B = P (cols q)
      o = MFMA16(bk1, pf1.v, o);
      float4 ov;
      ov.x = o[0]; ov.y = o[1]; ov.z = o[2]; ov.w = o[3];
      *(float4*)&ob[dt * 16 + hi * 4] = ov;
    }
    __builtin_amdgcn_s_setprio(0);

    if (i + 1 < NT) {
      LDS_BARRIER();     // BAR2: all PV reads of kT_lds done
      stage_kT(i + 1);   // re-read tile i+1 (L1/L2-hot) -> kT_lds
    }
  }
}

// ---------------------------------------------------------------------------
extern "C" void kernel_launch(void* const* d_in, const int* in_sizes, int n_in,
                              void* d_out, int out_size, void* d_ws, size_t ws_size,
                              hipStream_t stream) {
  const float* querys = (const float*)d_in[0];  // [16,128,768]
  const float* keys   = (const float*)d_in[1];  // [16,128,64,256]
  const float* Wq     = (const float*)d_in[2];  // [768,256]
  const float* Wk     = (const float*)d_in[3];  // [256,256]
  const float* Wm_w   = (const float*)d_in[4];  // [256]
  const float* Wm_b   = (const float*)d_in[5];  // [1]
  const int*   masks  = (const int*)d_in[6];    // [16,128,64]
  float* out = (float*)d_out;                   // [16,128,128,256]

  ushort* wfT   = (ushort*)d_ws;                          // 256*768 bf16
  ushort* qt_bf = (ushort*)((char*)d_ws + DK * DQ * 2);   // 2048*256 bf16

  k_wfuse<<<dim3(DK / 16, DQ / 64), 64, 0, stream>>>(Wq, Wk, wfT);
  k_qt<<<dim3((BB * EE) / 32, DK / 64), 128, 0, stream>>>(querys, wfT, qt_bf);
  k_attn<<<(BB * EE) / NT, 512, 0, stream>>>(keys, qt_bf, Wm_w, Wm_b, masks, out);
}

// Round 10
// 144.492 us; speedup vs baseline: 1.5707x; 1.2979x over previous
//
#include <hip/hip_runtime.h>
#include <hip/hip_bf16.h>

#define BB 16
#define EE 128
#define MM 64
#define DQ 768
#define DK 256

typedef __attribute__((ext_vector_type(8))) short short8v;    // 8 bf16 = 4 VGPR
typedef __attribute__((ext_vector_type(4))) float f32x4;
typedef __attribute__((ext_vector_type(16))) float f32x16;

#define MFMA16(a, b, c) __builtin_amdgcn_mfma_f32_16x16x32_bf16(a, b, c, 0, 0, 0)
#define MFMA32(a, b, c) __builtin_amdgcn_mfma_f32_32x32x16_bf16(a, b, c, 0, 0, 0)

// raw barrier: LDS visibility only; leaves global loads/stores in flight
#define LDS_BARRIER() asm volatile("s_waitcnt lgkmcnt(0)\n\ts_barrier" ::: "memory")

__device__ __forceinline__ ushort f2bf(float f) {
  __hip_bfloat16 h = __float2bfloat16(f);
  return *reinterpret_cast<ushort*>(&h);
}
__device__ __forceinline__ uint pack2(float lo, float hi) {
  return (uint)f2bf(lo) | ((uint)f2bf(hi) << 16);
}

// ---------------------------------------------------------------------------
// K1: WfT[e][d] = sum_k Wq[d][k] * Wk[e][k]  (= (Wq @ Wk^T)^T, bf16) via MFMA.
// ---------------------------------------------------------------------------
__global__ __launch_bounds__(64) void k_wfuse(const float* __restrict__ Wq,
                                              const float* __restrict__ Wk,
                                              ushort* __restrict__ wfT) {
  const int lane = threadIdx.x & 63;
  const int lo = lane & 15, hi = lane >> 4;
  const int e0 = blockIdx.x * 16;
  const int d0 = blockIdx.y * 64;
  f32x4 acc[4] = {f32x4{0.f, 0.f, 0.f, 0.f}, f32x4{0.f, 0.f, 0.f, 0.f},
                  f32x4{0.f, 0.f, 0.f, 0.f}, f32x4{0.f, 0.f, 0.f, 0.f}};
#pragma unroll
  for (int ks = 0; ks < 8; ++ks) {
    const int k = ks * 32 + 8 * hi;
    const float4 a0 = *(const float4*)&Wk[(size_t)(e0 + lo) * DK + k];
    const float4 a1 = *(const float4*)&Wk[(size_t)(e0 + lo) * DK + k + 4];
    union { short8v v; uint u[4]; } av;
    av.u[0] = pack2(a0.x, a0.y); av.u[1] = pack2(a0.z, a0.w);
    av.u[2] = pack2(a1.x, a1.y); av.u[3] = pack2(a1.z, a1.w);
#pragma unroll
    for (int dt = 0; dt < 4; ++dt) {
      const float4 b0 = *(const float4*)&Wq[(size_t)(d0 + dt * 16 + lo) * DK + k];
      const float4 b1 = *(const float4*)&Wq[(size_t)(d0 + dt * 16 + lo) * DK + k + 4];
      union { short8v v; uint u[4]; } bv;
      bv.u[0] = pack2(b0.x, b0.y); bv.u[1] = pack2(b0.z, b0.w);
      bv.u[2] = pack2(b1.x, b1.y); bv.u[3] = pack2(b1.z, b1.w);
      acc[dt] = MFMA16(av.v, bv.v, acc[dt]);
    }
  }
#pragma unroll
  for (int dt = 0; dt < 4; ++dt)
#pragma unroll
    for (int r = 0; r < 4; ++r)
      wfT[(size_t)(e0 + 4 * hi + r) * DQ + d0 + dt * 16 + lo] = f2bf(acc[dt][r]);
}

// ---------------------------------------------------------------------------
// K2: qt[r][e] = sum_d relu(querys[r][d]) * WfT[e][d], bf16 MFMA, no LDS.
// ---------------------------------------------------------------------------
__global__ __launch_bounds__(128) void k_qt(const float* __restrict__ querys,
                                            const ushort* __restrict__ wfT,
                                            ushort* __restrict__ qt) {
  const int tid = threadIdx.x;
  const int w = tid >> 6;
  const int lane = tid & 63;
  const int lo = lane & 15, hi = lane >> 4;
  const int r0 = blockIdx.x * 32 + w * 16;
  const int e0 = blockIdx.y * 64;
  const float* qrow = querys + (size_t)(r0 + lo) * DQ;
  f32x4 acc[4] = {f32x4{0.f, 0.f, 0.f, 0.f}, f32x4{0.f, 0.f, 0.f, 0.f},
                  f32x4{0.f, 0.f, 0.f, 0.f}, f32x4{0.f, 0.f, 0.f, 0.f}};
#pragma unroll
  for (int kc = 0; kc < DQ; kc += 32) {
    const int k = kc + 8 * hi;
    const float4 a0 = *(const float4*)&qrow[k];
    const float4 a1 = *(const float4*)&qrow[k + 4];
    union { short8v v; uint u[4]; } af;
    af.u[0] = pack2(fmaxf(a0.x, 0.f), fmaxf(a0.y, 0.f));
    af.u[1] = pack2(fmaxf(a0.z, 0.f), fmaxf(a0.w, 0.f));
    af.u[2] = pack2(fmaxf(a1.x, 0.f), fmaxf(a1.y, 0.f));
    af.u[3] = pack2(fmaxf(a1.z, 0.f), fmaxf(a1.w, 0.f));
#pragma unroll
    for (int et = 0; et < 4; ++et) {
      const short8v bf = *(const short8v*)&wfT[(size_t)(e0 + et * 16 + lo) * DQ + k];
      acc[et] = MFMA16(af.v, bf, acc[et]);
    }
  }
#pragma unroll
  for (int et = 0; et < 4; ++et)
#pragma unroll
    for (int r = 0; r < 4; ++r)
      qt[(size_t)(r0 + hi * 4 + r) * DK + e0 + et * 16 + lo] = f2bf(acc[et][r]);
}

// ---------------------------------------------------------------------------
// K3: fused MFMA attention. 512 thr = 8 waves, ONE (b,a) per block, grid 2048.
// LDS = relu 32K + kT 32K + P 16K = EXACTLY 80 KiB -> 2 blocks/CU, 16 waves/CU
// (max occupancy). Flow (3 raw barriers):
//   stage keys->relu+kT+bias | BAR1 | QK^T(swapped 16x16) -> in-lane softmax
//   (reads bias aliased in P rows 0-1) | BAR2 | P -> P_lds (swizzled bf16)
//   | BAR3 | PV via NON-swapped mfma_32x32x16: C[q][d], col=lane&31=d ->
//   every scalar store = 32 lanes x 4B = full aligned 128B line (2 lines per
//   instruction, ZERO partial-line writes — r8 showed +56MB write
//   amplification from the old 16-row x 64B scatter).
// ---------------------------------------------------------------------------
__global__ __launch_bounds__(512, 4) void k_attn(
    const float* __restrict__ keys, const ushort* __restrict__ qt,
    const float* __restrict__ wm_w, const float* __restrict__ wm_b,
    const int* __restrict__ masks, float* __restrict__ out) {
  __shared__ ushort relu_lds[MM * DK];   // 32 KiB, swz (m&7)<<4
  __shared__ ushort kT_lds[DK * MM];     // 32 KiB, swz ((d&7)^((d>>3)&7))<<4
  __shared__ ushort P_lds[EE * MM];      // 16 KiB, swz ((q&7)^((q>>3)&7))<<4
  float* biasf = (float*)P_lds;          // 64 f32 alias P rows 0-1 (q=0,1)

  const int tid = threadIdx.x;
  const int w = tid >> 6;
  const int lane = tid & 63;
  const int lo = lane & 15, hi = lane >> 4;
  const int ba = blockIdx.x;             // b*EE + a
  const int b = ba >> 7;

  // qt B-fragments for QK (cols q = w*16+lo); L2-resident
  const ushort* qrowp = qt + ((size_t)b * EE + w * 16 + lo) * DK + 8 * hi;
  short8v aq[8];
#pragma unroll
  for (int ks = 0; ks < 8; ++ks) aq[ks] = *(const short8v*)(qrowp + 32 * ks);

  // ================= stage: keys -> relu_lds + kT_lds + bias ===============
  // 16-lane group hi of wave w owns row pair (m0, m0+1); lane lo covers
  // float4 chunks c = lo + 16*it.
  {
    const int m0 = w * 8 + hi * 2;
    const float4* kb4 = (const float4*)(keys + (size_t)ba * (MM * DK));
    const float4* wm4p = (const float4*)wm_w;
    float bp0 = 0.f, bp1 = 0.f;
#pragma unroll
    for (int it = 0; it < 4; ++it) {
      const int c = lo + 16 * it;
      const float4 va = kb4[(size_t)m0 * 64 + c];
      const float4 vb = kb4[(size_t)(m0 + 1) * 64 + c];
      const float4 wm4 = wm4p[c];
      const float rx0 = fmaxf(va.x, 0.f), ry0 = fmaxf(va.y, 0.f);
      const float rz0 = fmaxf(va.z, 0.f), rw0 = fmaxf(va.w, 0.f);
      const float rx1 = fmaxf(vb.x, 0.f), ry1 = fmaxf(vb.y, 0.f);
      const float rz1 = fmaxf(vb.z, 0.f), rw1 = fmaxf(vb.w, 0.f);
      bp0 += rx0 * wm4.x + ry0 * wm4.y + rz0 * wm4.z + rw0 * wm4.w;
      bp1 += rx1 * wm4.x + ry1 * wm4.y + rz1 * wm4.z + rw1 * wm4.w;
      uint2 ra, rb;
      ra.x = pack2(rx0, ry0); ra.y = pack2(rz0, rw0);
      rb.x = pack2(rx1, ry1); rb.y = pack2(rz1, rw1);
      *(uint2*)((char*)relu_lds + (size_t)m0 * 512 +
                ((8 * c) ^ ((m0 & 7) << 4))) = ra;
      *(uint2*)((char*)relu_lds + (size_t)(m0 + 1) * 512 +
                ((8 * c) ^ (((m0 + 1) & 7) << 4))) = rb;
      const float va4[4] = {va.x, va.y, va.z, va.w};
      const float vb4[4] = {vb.x, vb.y, vb.z, vb.w};
#pragma unroll
      for (int j = 0; j < 4; ++j) {
        const int d = 4 * c + j;
        const int sw = ((d & 7) ^ ((d >> 3) & 7)) << 4;
        *(uint*)((char*)kT_lds + (size_t)d * 128 + ((2 * m0) ^ sw)) =
            pack2(va4[j], vb4[j]);
      }
    }
    bp0 += __shfl_xor(bp0, 1); bp1 += __shfl_xor(bp1, 1);
    bp0 += __shfl_xor(bp0, 2); bp1 += __shfl_xor(bp1, 2);
    bp0 += __shfl_xor(bp0, 4); bp1 += __shfl_xor(bp1, 4);
    bp0 += __shfl_xor(bp0, 8); bp1 += __shfl_xor(bp1, 8);
    if (lo == 0) {
      const float wmb = wm_b[0];
      const int mk0 = masks[(size_t)ba * MM + m0];
      const int mk1 = masks[(size_t)ba * MM + m0 + 1];
      biasf[m0]     = mk0 ? (bp0 + wmb) : -1e12f;
      biasf[m0 + 1] = mk1 ? (bp1 + wmb) : -1e12f;
    }
  }
  LDS_BARRIER();   // BAR1: staging + bias visible

  // ================= QK^T swapped 16x16: S^T[m][q], lane q = w*16+lo =======
  f32x4 sacc[4] = {f32x4{0.f, 0.f, 0.f, 0.f}, f32x4{0.f, 0.f, 0.f, 0.f},
                   f32x4{0.f, 0.f, 0.f, 0.f}, f32x4{0.f, 0.f, 0.f, 0.f}};
  __builtin_amdgcn_s_setprio(1);
#pragma unroll
  for (int ks = 0; ks < 8; ++ks) {
#pragma unroll
    for (int mt = 0; mt < 4; ++mt) {
      const int m = mt * 16 + lo;
      const int k = ks * 32 + 8 * hi;
      const short8v bf = *(const short8v*)((char*)relu_lds + (size_t)m * 512 +
                                           ((2 * k) ^ ((m & 7) << 4)));
      sacc[mt] = MFMA16(bf, aq[ks], sacc[mt]);  // A = relu_k (rows m), B = qt
    }
  }
  __builtin_amdgcn_s_setprio(0);

  // ================= softmax: in-lane over 16 m + shfl_xor 16,32 ===========
  const float scale = 0.036084391824351615f;  // 1/sqrt(768)
  float l[4][4];
  float mx = -3.4e38f;
#pragma unroll
  for (int mt = 0; mt < 4; ++mt) {
    const float4 bv = *(const float4*)&biasf[mt * 16 + hi * 4];
    const float bv4[4] = {bv.x, bv.y, bv.z, bv.w};
#pragma unroll
    for (int r = 0; r < 4; ++r) {
      l[mt][r] = fmaf(sacc[mt][r], scale, bv4[r]);
      mx = fmaxf(mx, l[mt][r]);
    }
  }
  mx = fmaxf(mx, __shfl_xor(mx, 16));
  mx = fmaxf(mx, __shfl_xor(mx, 32));
  float s = 0.f;
#pragma unroll
  for (int mt = 0; mt < 4; ++mt)
#pragma unroll
    for (int r = 0; r < 4; ++r) {
      l[mt][r] = __expf(l[mt][r] - mx);
      s += l[mt][r];
    }
  s += __shfl_xor(s, 16);
  s += __shfl_xor(s, 32);
  const float rinv = 1.f / s;

  uint pk0[4], pk1[4];
#pragma unroll
  for (int mt = 0; mt < 4; ++mt) {
    pk0[mt] = pack2(l[mt][0] * rinv, l[mt][1] * rinv);
    pk1[mt] = pack2(l[mt][2] * rinv, l[mt][3] * rinv);
  }

  LDS_BARRIER();   // BAR2: all bias reads done; P region may be overwritten

  // ================= P -> P_lds (bf16, swizzled rows of 128B) ==============
  {
    const int q = w * 16 + lo;
    const int swq = ((q & 7) ^ ((q >> 3) & 7)) << 4;
#pragma unroll
    for (int mt = 0; mt < 4; ++mt) {
      uint2 pv; pv.x = pk0[mt]; pv.y = pk1[mt];   // m = mt*16+hi*4 .. +3
      *(uint2*)((char*)P_lds + (size_t)q * 128 +
                ((32 * mt + 8 * hi) ^ swq)) = pv;
    }
  }
  LDS_BARRIER();   // BAR3: P complete

  // ================= PV: NON-swapped 32x32x16, C[q][d] =====================
  // wave w: q-block qb=(w&3)*32, d-range db=(w>>2)*128 (4 tiles of 32 d).
  // A (P): row q = qb + (lane&31), k m = ms*16 + 8*(lane>>5) + j
  // B (kT): col d = db + t*32 + (lane&31), same k
  // C: col d = lane&31 -> each per-reg store = 32 consecutive d = 128B line.
  {
    const int l31 = lane & 31, lh = lane >> 5;
    const int qb = (w & 3) * 32;
    const int db = (w >> 2) * 128;
    const int qa = qb + l31;
    const int swqa = ((qa & 7) ^ ((qa >> 3) & 7)) << 4;
    short8v pa[4];
#pragma unroll
    for (int ms = 0; ms < 4; ++ms)
      pa[ms] = *(const short8v*)((char*)P_lds + (size_t)qa * 128 +
                                 ((32 * ms + 16 * lh) ^ swqa));
    float* ob = out + (size_t)ba * EE * DK;
    __builtin_amdgcn_s_setprio(1);
#pragma unroll
    for (int t = 0; t < 4; ++t) {
      const int d = db + t * 32 + l31;
      const int swd = ((d & 7) ^ ((d >> 3) & 7)) << 4;
      f32x16 o = 0.f;
#pragma unroll
      for (int ms = 0; ms < 4; ++ms) {
        const short8v bk = *(const short8v*)((char*)kT_lds + (size_t)d * 128 +
                                             ((32 * ms + 16 * lh) ^ swd));
        o = MFMA32(pa[ms], bk, o);
      }
#pragma unroll
      for (int r = 0; r < 16; ++r) {
        const int qrow = qb + (r & 3) + 8 * (r >> 2) + 4 * lh;
        ob[(size_t)qrow * DK + d] = o[r];
      }
    }
    __builtin_amdgcn_s_setprio(0);
  }
}

// ---------------------------------------------------------------------------
extern "C" void kernel_launch(void* const* d_in, const int* in_sizes, int n_in,
                              void* d_out, int out_size, void* d_ws, size_t ws_size,
                              hipStream_t stream) {
  const float* querys = (const float*)d_in[0];  // [16,128,768]
  const float* keys   = (const float*)d_in[1];  // [16,128,64,256]
  const float* Wq     = (const float*)d_in[2];  // [768,256]
  const float* Wk     = (const float*)d_in[3];  // [256,256]
  const float* Wm_w   = (const float*)d_in[4];  // [256]
  const float* Wm_b   = (const float*)d_in[5];  // [1]
  const int*   masks  = (const int*)d_in[6];    // [16,128,64]
  float* out = (float*)d_out;                   // [16,128,128,256]

  ushort* wfT   = (ushort*)d_ws;                          // 256*768 bf16
  ushort* qt_bf = (ushort*)((char*)d_ws + DK * DQ * 2);   // 2048*256 bf16

  k_wfuse<<<dim3(DK / 16, DQ / 64), 64, 0, stream>>>(Wq, Wk, wfT);
  k_qt<<<dim3((BB * EE) / 32, DK / 64), 128, 0, stream>>>(querys, wfT, qt_bf);
  k_attn<<<BB * EE, 512, 0, stream>>>(keys, qt_bf, Wm_w, Wm_b, masks, out);
}

// Round 11
// 141.686 us; speedup vs baseline: 1.6018x; 1.0198x over previous
//
#include <hip/hip_runtime.h>
#include <hip/hip_bf16.h>

#define BB 16
#define EE 128
#define MM 64
#define DQ 768
#define DK 256

typedef __attribute__((ext_vector_type(8))) short short8v;    // 8 bf16 = 4 VGPR
typedef __attribute__((ext_vector_type(4))) float f32x4;
typedef __attribute__((ext_vector_type(16))) float f32x16;

#define MFMA16(a, b, c) __builtin_amdgcn_mfma_f32_16x16x32_bf16(a, b, c, 0, 0, 0)
#define MFMA32(a, b, c) __builtin_amdgcn_mfma_f32_32x32x16_bf16(a, b, c, 0, 0, 0)

// raw barrier: LDS visibility only; leaves global loads/stores in flight
#define LDS_BARRIER() asm volatile("s_waitcnt lgkmcnt(0)\n\ts_barrier" ::: "memory")

__device__ __forceinline__ ushort f2bf(float f) {
  __hip_bfloat16 h = __float2bfloat16(f);
  return *reinterpret_cast<ushort*>(&h);
}
__device__ __forceinline__ uint pack2(float lo, float hi) {
  return (uint)f2bf(lo) | ((uint)f2bf(hi) << 16);
}

// ---------------------------------------------------------------------------
// K1: WfT[e][d] = sum_k Wq[d][k] * Wk[e][k]  (= (Wq @ Wk^T)^T, bf16) via MFMA.
// ---------------------------------------------------------------------------
__global__ __launch_bounds__(64) void k_wfuse(const float* __restrict__ Wq,
                                              const float* __restrict__ Wk,
                                              ushort* __restrict__ wfT) {
  const int lane = threadIdx.x & 63;
  const int lo = lane & 15, hi = lane >> 4;
  const int e0 = blockIdx.x * 16;
  const int d0 = blockIdx.y * 64;
  f32x4 acc[4] = {f32x4{0.f, 0.f, 0.f, 0.f}, f32x4{0.f, 0.f, 0.f, 0.f},
                  f32x4{0.f, 0.f, 0.f, 0.f}, f32x4{0.f, 0.f, 0.f, 0.f}};
#pragma unroll
  for (int ks = 0; ks < 8; ++ks) {
    const int k = ks * 32 + 8 * hi;
    const float4 a0 = *(const float4*)&Wk[(size_t)(e0 + lo) * DK + k];
    const float4 a1 = *(const float4*)&Wk[(size_t)(e0 + lo) * DK + k + 4];
    union { short8v v; uint u[4]; } av;
    av.u[0] = pack2(a0.x, a0.y); av.u[1] = pack2(a0.z, a0.w);
    av.u[2] = pack2(a1.x, a1.y); av.u[3] = pack2(a1.z, a1.w);
#pragma unroll
    for (int dt = 0; dt < 4; ++dt) {
      const float4 b0 = *(const float4*)&Wq[(size_t)(d0 + dt * 16 + lo) * DK + k];
      const float4 b1 = *(const float4*)&Wq[(size_t)(d0 + dt * 16 + lo) * DK + k + 4];
      union { short8v v; uint u[4]; } bv;
      bv.u[0] = pack2(b0.x, b0.y); bv.u[1] = pack2(b0.z, b0.w);
      bv.u[2] = pack2(b1.x, b1.y); bv.u[3] = pack2(b1.z, b1.w);
      acc[dt] = MFMA16(av.v, bv.v, acc[dt]);
    }
  }
#pragma unroll
  for (int dt = 0; dt < 4; ++dt)
#pragma unroll
    for (int r = 0; r < 4; ++r)
      wfT[(size_t)(e0 + 4 * hi + r) * DQ + d0 + dt * 16 + lo] = f2bf(acc[dt][r]);
}

// ---------------------------------------------------------------------------
// K2: qt2[r][e] = (sum_d relu(querys[r][d]) * WfT[e][d]) * scale + Wm_w[e].
// Folding scale AND the mention-bias weight into the query side makes QK^T
// emit the complete pre-mask logit (wm_b is a row-constant -> softmax no-op).
// Fold done in f32 before the bf16 cast.
// ---------------------------------------------------------------------------
__global__ __launch_bounds__(128) void k_qt(const float* __restrict__ querys,
                                            const ushort* __restrict__ wfT,
                                            const float* __restrict__ wm_w,
                                            ushort* __restrict__ qt) {
  const int tid = threadIdx.x;
  const int w = tid >> 6;
  const int lane = tid & 63;
  const int lo = lane & 15, hi = lane >> 4;
  const int r0 = blockIdx.x * 32 + w * 16;
  const int e0 = blockIdx.y * 64;
  const float* qrow = querys + (size_t)(r0 + lo) * DQ;
  f32x4 acc[4] = {f32x4{0.f, 0.f, 0.f, 0.f}, f32x4{0.f, 0.f, 0.f, 0.f},
                  f32x4{0.f, 0.f, 0.f, 0.f}, f32x4{0.f, 0.f, 0.f, 0.f}};
#pragma unroll
  for (int kc = 0; kc < DQ; kc += 32) {
    const int k = kc + 8 * hi;
    const float4 a0 = *(const float4*)&qrow[k];
    const float4 a1 = *(const float4*)&qrow[k + 4];
    union { short8v v; uint u[4]; } af;
    af.u[0] = pack2(fmaxf(a0.x, 0.f), fmaxf(a0.y, 0.f));
    af.u[1] = pack2(fmaxf(a0.z, 0.f), fmaxf(a0.w, 0.f));
    af.u[2] = pack2(fmaxf(a1.x, 0.f), fmaxf(a1.y, 0.f));
    af.u[3] = pack2(fmaxf(a1.z, 0.f), fmaxf(a1.w, 0.f));
#pragma unroll
    for (int et = 0; et < 4; ++et) {
      const short8v bf = *(const short8v*)&wfT[(size_t)(e0 + et * 16 + lo) * DQ + k];
      acc[et] = MFMA16(af.v, bf, acc[et]);
    }
  }
  const float sc = 0.036084391824351615f;  // 1/sqrt(768)
#pragma unroll
  for (int et = 0; et < 4; ++et) {
    const float wmv = wm_w[e0 + et * 16 + lo];
#pragma unroll
    for (int r = 0; r < 4; ++r)
      qt[(size_t)(r0 + hi * 4 + r) * DK + e0 + et * 16 + lo] =
          f2bf(fmaf(acc[et][r], sc, wmv));
  }
}

// ---------------------------------------------------------------------------
// K3: fused MFMA attention. 512 thr = 8 waves, ONE (b,a) per block, grid 2048.
// LDS = relu 32K + kT 32K + P 16K = exactly 80 KiB -> 2 blocks/CU, 16 waves.
// Bias machinery fully deleted (folded into qt2 by K2); mask applied
// in-register during softmax from 4 int4 loads. Flow (2 raw barriers):
//   stage keys->relu+kT | BAR1 | QK^T(swapped 16x16, full logits) ->
//   in-lane softmax(+mask) -> P -> P_lds | BAR2 | PV 32x32 C[q][d]:
//   every per-reg store = 32 lanes x 4B = full aligned 128B line.
// ---------------------------------------------------------------------------
__global__ __launch_bounds__(512, 4) void k_attn(
    const float* __restrict__ keys, const ushort* __restrict__ qt,
    const int* __restrict__ masks, float* __restrict__ out) {
  __shared__ ushort relu_lds[MM * DK];   // 32 KiB, swz (m&7)<<4
  __shared__ ushort kT_lds[DK * MM];     // 32 KiB, swz ((d&7)^((d>>3)&7))<<4
  __shared__ ushort P_lds[EE * MM];      // 16 KiB, swz ((q&7)^((q>>3)&7))<<4

  const int tid = threadIdx.x;
  const int w = tid >> 6;
  const int lane = tid & 63;
  const int lo = lane & 15, hi = lane >> 4;
  const int ba = blockIdx.x;             // b*EE + a
  const int b = ba >> 7;

  // qt2 B-fragments for QK (cols q = w*16+lo); L2-resident
  const ushort* qrowp = qt + ((size_t)b * EE + w * 16 + lo) * DK + 8 * hi;
  short8v aq[8];
#pragma unroll
  for (int ks = 0; ks < 8; ++ks) aq[ks] = *(const short8v*)(qrowp + 32 * ks);

  // mask bits for this lane's softmax rows: m = mt*16 + hi*4 .. +3
  const int4* mrow = (const int4*)(masks + (size_t)ba * MM);
  int4 mk4[4];
#pragma unroll
  for (int mt = 0; mt < 4; ++mt) mk4[mt] = mrow[mt * 4 + hi];

  // ================= stage: keys -> relu_lds + kT_lds ======================
  // 16-lane group hi of wave w owns row pair (m0, m0+1); lane lo covers
  // float4 chunks c = lo + 16*it.
  {
    const int m0 = w * 8 + hi * 2;
    const float4* kb4 = (const float4*)(keys + (size_t)ba * (MM * DK));
#pragma unroll
    for (int it = 0; it < 4; ++it) {
      const int c = lo + 16 * it;
      const float4 va = kb4[(size_t)m0 * 64 + c];
      const float4 vb = kb4[(size_t)(m0 + 1) * 64 + c];
      uint2 ra, rb;
      ra.x = pack2(fmaxf(va.x, 0.f), fmaxf(va.y, 0.f));
      ra.y = pack2(fmaxf(va.z, 0.f), fmaxf(va.w, 0.f));
      rb.x = pack2(fmaxf(vb.x, 0.f), fmaxf(vb.y, 0.f));
      rb.y = pack2(fmaxf(vb.z, 0.f), fmaxf(vb.w, 0.f));
      *(uint2*)((char*)relu_lds + (size_t)m0 * 512 +
                ((8 * c) ^ ((m0 & 7) << 4))) = ra;
      *(uint2*)((char*)relu_lds + (size_t)(m0 + 1) * 512 +
                ((8 * c) ^ (((m0 + 1) & 7) << 4))) = rb;
      const float va4[4] = {va.x, va.y, va.z, va.w};
      const float vb4[4] = {vb.x, vb.y, vb.z, vb.w};
#pragma unroll
      for (int j = 0; j < 4; ++j) {
        const int d = 4 * c + j;
        const int sw = ((d & 7) ^ ((d >> 3) & 7)) << 4;
        *(uint*)((char*)kT_lds + (size_t)d * 128 + ((2 * m0) ^ sw)) =
            pack2(va4[j], vb4[j]);
      }
    }
  }
  LDS_BARRIER();   // BAR1: staging visible

  // ====== QK^T swapped 16x16: full logits S^T[m][q], lane q = w*16+lo ======
  f32x4 sacc[4] = {f32x4{0.f, 0.f, 0.f, 0.f}, f32x4{0.f, 0.f, 0.f, 0.f},
                   f32x4{0.f, 0.f, 0.f, 0.f}, f32x4{0.f, 0.f, 0.f, 0.f}};
  __builtin_amdgcn_s_setprio(1);
#pragma unroll
  for (int ks = 0; ks < 8; ++ks) {
#pragma unroll
    for (int mt = 0; mt < 4; ++mt) {
      const int m = mt * 16 + lo;
      const int k = ks * 32 + 8 * hi;
      const short8v bf = *(const short8v*)((char*)relu_lds + (size_t)m * 512 +
                                           ((2 * k) ^ ((m & 7) << 4)));
      sacc[mt] = MFMA16(bf, aq[ks], sacc[mt]);  // A = relu_k (rows m), B = qt2
    }
  }
  __builtin_amdgcn_s_setprio(0);

  // ============ softmax: mask select, in-lane 16 m + shfl_xor 16,32 ========
  float l[4][4];
  float mx = -3.4e38f;
#pragma unroll
  for (int mt = 0; mt < 4; ++mt) {
    const int mkb[4] = {mk4[mt].x, mk4[mt].y, mk4[mt].z, mk4[mt].w};
#pragma unroll
    for (int r = 0; r < 4; ++r) {
      l[mt][r] = (mkb[r] != 0) ? sacc[mt][r] : -1e30f;
      mx = fmaxf(mx, l[mt][r]);
    }
  }
  mx = fmaxf(mx, __shfl_xor(mx, 16));
  mx = fmaxf(mx, __shfl_xor(mx, 32));
  float s = 0.f;
#pragma unroll
  for (int mt = 0; mt < 4; ++mt)
#pragma unroll
    for (int r = 0; r < 4; ++r) {
      l[mt][r] = __expf(l[mt][r] - mx);
      s += l[mt][r];
    }
  s += __shfl_xor(s, 16);
  s += __shfl_xor(s, 32);
  const float rinv = 1.f / s;

  // ================= P -> P_lds (bf16, swizzled rows of 128B) ==============
  {
    const int q = w * 16 + lo;
    const int swq = ((q & 7) ^ ((q >> 3) & 7)) << 4;
#pragma unroll
    for (int mt = 0; mt < 4; ++mt) {
      uint2 pv;
      pv.x = pack2(l[mt][0] * rinv, l[mt][1] * rinv);
      pv.y = pack2(l[mt][2] * rinv, l[mt][3] * rinv);  // m = mt*16+hi*4 .. +3
      *(uint2*)((char*)P_lds + (size_t)q * 128 +
                ((32 * mt + 8 * hi) ^ swq)) = pv;
    }
  }
  LDS_BARRIER();   // BAR2: P complete

  // ================= PV: NON-swapped 32x32x16, C[q][d] =====================
  // wave w: q-block qb=(w&3)*32, d-range db=(w>>2)*128 (4 tiles of 32 d).
  // C: col d = lane&31 -> each per-reg store = 32 consecutive d = 128B line.
  {
    const int l31 = lane & 31, lh = lane >> 5;
    const int qb = (w & 3) * 32;
    const int db = (w >> 2) * 128;
    const int qa = qb + l31;
    const int swqa = ((qa & 7) ^ ((qa >> 3) & 7)) << 4;
    short8v pa[4];
#pragma unroll
    for (int ms = 0; ms < 4; ++ms)
      pa[ms] = *(const short8v*)((char*)P_lds + (size_t)qa * 128 +
                                 ((32 * ms + 16 * lh) ^ swqa));
    float* ob = out + (size_t)ba * EE * DK;
    __builtin_amdgcn_s_setprio(1);
#pragma unroll
    for (int t = 0; t < 4; ++t) {
      const int d = db + t * 32 + l31;
      const int swd = ((d & 7) ^ ((d >> 3) & 7)) << 4;
      f32x16 o = 0.f;
#pragma unroll
      for (int ms = 0; ms < 4; ++ms) {
        const short8v bk = *(const short8v*)((char*)kT_lds + (size_t)d * 128 +
                                             ((32 * ms + 16 * lh) ^ swd));
        o = MFMA32(pa[ms], bk, o);
      }
#pragma unroll
      for (int r = 0; r < 16; ++r) {
        const int qrow = qb + (r & 3) + 8 * (r >> 2) + 4 * lh;
        ob[(size_t)qrow * DK + d] = o[r];
      }
    }
    __builtin_amdgcn_s_setprio(0);
  }
}

// ---------------------------------------------------------------------------
extern "C" void kernel_launch(void* const* d_in, const int* in_sizes, int n_in,
                              void* d_out, int out_size, void* d_ws, size_t ws_size,
                              hipStream_t stream) {
  const float* querys = (const float*)d_in[0];  // [16,128,768]
  const float* keys   = (const float*)d_in[1];  // [16,128,64,256]
  const float* Wq     = (const float*)d_in[2];  // [768,256]
  const float* Wk     = (const float*)d_in[3];  // [256,256]
  const float* Wm_w   = (const float*)d_in[4];  // [256]
  // d_in[5] = Wm_b: row-constant logit shift -> cancels in softmax; unused.
  const int*   masks  = (const int*)d_in[6];    // [16,128,64]
  float* out = (float*)d_out;                   // [16,128,128,256]

  ushort* wfT   = (ushort*)d_ws;                          // 256*768 bf16
  ushort* qt_bf = (ushort*)((char*)d_ws + DK * DQ * 2);   // 2048*256 bf16

  k_wfuse<<<dim3(DK / 16, DQ / 64), 64, 0, stream>>>(Wq, Wk, wfT);
  k_qt<<<dim3((BB * EE) / 32, DK / 64), 128, 0, stream>>>(querys, wfT, Wm_w, qt_bf);
  k_attn<<<BB * EE, 512, 0, stream>>>(keys, qt_bf, masks, out);
}